// Round 3
// baseline (225.279 us; speedup 1.0000x reference)
//
#include <hip/hip_runtime.h>

#define ROW_LEN 8192
#define TOPK 8
#define THREADS 256
#define NWAVES (THREADS / 64)
#define WCAP 96   // per-wave candidate cap; E[count]≈20, Poisson tail past 96 ~1e-30

__global__ __launch_bounds__(THREADS) void topk_rows_kernel(
        const float* __restrict__ x,
        float* __restrict__ out_vals,     // [n_rows, 8] float
        float* __restrict__ out_idx,      // [n_rows, 8] indices stored as float
        int n_rows) {
    const int row  = blockIdx.x;
    const int tid  = threadIdx.x;
    const int lane = tid & 63;
    const int wave = tid >> 6;
    if (row >= n_rows) return;

    const float4* rowp = (const float4*)(x + (size_t)row * ROW_LEN);

    // ---- load 32 elements into registers, coalesced float4 ----
    float v[32];
#pragma unroll
    for (int k = 0; k < 8; k++) {
        float4 f = rowp[k * THREADS + tid];
        v[4 * k + 0] = f.x; v[4 * k + 1] = f.y;
        v[4 * k + 2] = f.z; v[4 * k + 3] = f.w;
    }

    // ---- per-thread max (31 fmax) ----
    float mx = v[0];
#pragma unroll
    for (int e = 1; e < 32; e++) mx = fmaxf(mx, v[e]);

    // ---- conservative wave threshold in 6 shfls:
    // T = min over the 8 lane-groups (lanes 8g..8g+7, 256 elems each) of the
    // group max. The 8 group-maxima are 8 distinct row positions all >= T,
    // so the row's 8th-largest >= T -> every top-8 element passes val >= T.
    float m = mx;
#pragma unroll
    for (int d = 1; d <= 4; d <<= 1) m = fmaxf(m, __shfl_xor(m, d, 64));
#pragma unroll
    for (int d = 8; d <= 32; d <<= 1) m = fminf(m, __shfl_xor(m, d, 64));
    const float T = m;   // identical on all 64 lanes

    __shared__ float cv[NWAVES][WCAP];
    __shared__ int   ci[NWAVES][WCAP];
    __shared__ int   wn[NWAVES];

    // ---- candidate collection: ballot-aggregated compaction, no atomics ----
    int base = 0;   // wave-uniform running count
#pragma unroll
    for (int k = 0; k < 8; k++) {
#pragma unroll
        for (int j = 0; j < 4; j++) {
            const float val = v[4 * k + j];
            const bool pred = val >= T;
            const unsigned long long mask = __ballot(pred);
            if (mask) {                      // wave-uniform branch, ~25% taken
                if (pred) {
                    int slot = base + (int)__popcll(mask & ((1ull << lane) - 1));
                    if (slot < WCAP) {       // memory-safety clamp only
                        cv[wave][slot] = val;
                        ci[wave][slot] = 4 * (k * THREADS + tid) + j;
                    }
                }
                base += (int)__popcll(mask);
            }
        }
    }
    if (lane == 0) wn[wave] = (base < WCAP) ? base : WCAP;
    __syncthreads();   // the only barrier

    // ---- wave-0 parallel rank-select: rank by (value desc, index asc).
    // Ranks unique via index tiebreak -> exactly 8 race-free writers.
    if (wave == 0) {
        int cnt[NWAVES];
        int n = 0;
#pragma unroll
        for (int w = 0; w < NWAVES; w++) { cnt[w] = wn[w]; n += cnt[w]; }

        for (int c = lane; c < n; c += 64) {
            int w = 0, off = c;
            while (off >= cnt[w]) { off -= cnt[w]; w++; }
            const float myv = cv[w][off];
            const int   myi = ci[w][off];
            int rank = 0;
#pragma unroll
            for (int w2 = 0; w2 < NWAVES; w2++) {
                const int nn = cnt[w2];
                for (int j = 0; j < nn; j++) {
                    const float ov = cv[w2][j];
                    const int   oi = ci[w2][j];
                    rank += (ov > myv) || (ov == myv && oi < myi);
                }
            }
            if (rank < TOPK) {
                out_vals[(size_t)row * TOPK + rank] = myv;
                out_idx[(size_t)row * TOPK + rank]  = (float)myi;
            }
        }
    }
}

extern "C" void kernel_launch(void* const* d_in, const int* in_sizes, int n_in,
                              void* d_out, int out_size, void* d_ws, size_t ws_size,
                              hipStream_t stream) {
    const float* x = (const float*)d_in[0];
    float* out = (float*)d_out;
    const int n_rows = in_sizes[0] / ROW_LEN;          // 4096
    float* out_vals = out;                              // values, flat [n_rows*8]
    float* out_idx  = out + (size_t)n_rows * TOPK;      // indices (as float)

    topk_rows_kernel<<<n_rows, THREADS, 0, stream>>>(x, out_vals, out_idx, n_rows);
}

// Round 4
// 199.153 us; speedup vs baseline: 1.1312x; 1.1312x over previous
//
#include <hip/hip_runtime.h>

#define ROW_LEN 8192
#define TOPK 8
#define THREADS 256
#define CAND_CAP 256   // E[count]≈80 for Gaussian rows; Poisson tail past 256 negligible

__global__ __launch_bounds__(THREADS) void topk_rows_kernel(
        const float* __restrict__ x,
        float* __restrict__ out_vals,     // [n_rows, 8] float
        float* __restrict__ out_idx,      // [n_rows, 8] indices stored as float
        int n_rows) {
    const int row = blockIdx.x;
    const int tid = threadIdx.x;
    if (row >= n_rows) return;

    const float4* rowp = (const float4*)(x + (size_t)row * ROW_LEN);

    __shared__ int   cnt;
    __shared__ float cand_v[CAND_CAP];
    __shared__ int   cand_i[CAND_CAP];
    if (tid == 0) cnt = 0;

    // ---- phase 1: pure streaming load + per-thread max (no values kept live;
    // compiler needs only the loads in flight -> deep pipelining, low VGPR) ----
    float mx = -INFINITY;
#pragma unroll
    for (int k = 0; k < 8; k++) {
        float4 f = rowp[k * THREADS + tid];
        mx = fmaxf(mx, fmaxf(fmaxf(f.x, f.y), fmaxf(f.z, f.w)));
    }

    // ---- conservative wave threshold in 6 shfls:
    // T = min over the 8 lane-groups (8 lanes x 32 elems = 256 elems each) of
    // the group max. The 8 group maxima are 8 distinct row positions all >= T,
    // so the row's 8th-largest >= T -> every top-8 element passes val >= T.
    float m = mx;
#pragma unroll
    for (int d = 1; d <= 4; d <<= 1) m = fmaxf(m, __shfl_xor(m, d, 64));
#pragma unroll
    for (int d = 8; d <= 32; d <<= 1) m = fminf(m, __shfl_xor(m, d, 64));
    const float T = m;   // identical on all 64 lanes

    __syncthreads();   // cnt initialized (also orders phase-1/phase-2)

    // ---- phase 2: only threads whose max passes can hold candidates (~30/256).
    // Their re-loads (compiler rematerializes) hit L1/L2 — the row was just read
    // by this CU. ~34 LDS atomics per block total.
    if (mx >= T) {
#pragma unroll
        for (int k = 0; k < 8; k++) {
            float4 f = rowp[k * THREADS + tid];
            float vv[4] = {f.x, f.y, f.z, f.w};
#pragma unroll
            for (int j = 0; j < 4; j++) {
                if (vv[j] >= T) {
                    int p = atomicAdd(&cnt, 1);
                    if (p < CAND_CAP) {
                        cand_v[p] = vv[j];
                        cand_i[p] = 4 * (k * THREADS + tid) + j;
                    }
                }
            }
        }
    }
    __syncthreads();

    // ---- wave-0 parallel rank-select: rank by (value desc, index asc).
    // Ranks unique via index tiebreak -> exactly 8 race-free writers.
    if (tid < 64) {
        int n = cnt;
        if (n > CAND_CAP) n = CAND_CAP;
        for (int c = tid; c < n; c += 64) {
            const float myv = cand_v[c];
            const int   myi = cand_i[c];
            int rank = 0;
            for (int j = 0; j < n; j++) {
                const float ov = cand_v[j];
                const int   oi = cand_i[j];
                rank += (ov > myv) || (ov == myv && oi < myi);
            }
            if (rank < TOPK) {
                out_vals[(size_t)row * TOPK + rank] = myv;
                out_idx[(size_t)row * TOPK + rank]  = (float)myi;
            }
        }
    }
}

extern "C" void kernel_launch(void* const* d_in, const int* in_sizes, int n_in,
                              void* d_out, int out_size, void* d_ws, size_t ws_size,
                              hipStream_t stream) {
    const float* x = (const float*)d_in[0];
    float* out = (float*)d_out;
    const int n_rows = in_sizes[0] / ROW_LEN;          // 4096
    float* out_vals = out;                              // values, flat [n_rows*8]
    float* out_idx  = out + (size_t)n_rows * TOPK;      // indices (as float)

    topk_rows_kernel<<<n_rows, THREADS, 0, stream>>>(x, out_vals, out_idx, n_rows);
}